// Round 3
// baseline (238.951 us; speedup 1.0000x reference)
//
#include <hip/hip_runtime.h>

// Problem constants (fixed by setup_inputs)
#define NB   8      // batch
#define NN   1024   // nodes
#define DIN  256
#define DOUT 256
#define NH   8      // heads
#define DH   32     // head dim
constexpr float LN_EPS   = 1e-5f;
constexpr float QK_SCALE = 0.17677669529663687f; // 1/sqrt(32)

typedef __attribute__((ext_vector_type(8))) short s16x8;   // 8 bf16 (4 VGPR)
typedef __attribute__((ext_vector_type(4))) float f32x4;   // MFMA acc

__device__ __forceinline__ unsigned short f2bf(float f) {  // RNE fp32->bf16
    unsigned int u = __float_as_uint(f);
    u += 0x7FFFu + ((u >> 16) & 1u);
    return (unsigned short)(u >> 16);
}
__device__ __forceinline__ float bf2f(unsigned short h) {
    return __uint_as_float(((unsigned int)h) << 16);
}
__device__ __forceinline__ unsigned int packbf(float a, float b) {
    return (unsigned int)f2bf(a) | ((unsigned int)f2bf(b) << 16);
}

// ---------------------------------------------------------------------------
// Kernel 1: weight convert.  W (256x256, [k][n] fp32) -> Wt [n][k] bf16 hi/lo.
// Per matrix: hi block 65536 shorts, then lo block 65536.  4 matrices.
// ---------------------------------------------------------------------------
__global__ __launch_bounds__(256) void wsplit_kernel(
    const float* __restrict__ W0, const float* __restrict__ W1,
    const float* __restrict__ W2, const float* __restrict__ W3,
    unsigned short* __restrict__ Wt)
{
    const int mat = blockIdx.z;
    const int k0 = blockIdx.x * 64, n0 = blockIdx.y * 64;
    const float* W = (mat==0)?W0:(mat==1)?W1:(mat==2)?W2:W3;
    __shared__ float T[64][65];
    const int t = threadIdx.x;
    {
        const int r = t >> 2, cs = (t & 3) * 16;
        const float* src = W + (k0 + r)*256 + n0 + cs;
#pragma unroll
        for (int i = 0; i < 4; ++i) {
            float4 v = *(const float4*)(src + i*4);
            T[r][cs+i*4+0] = v.x; T[r][cs+i*4+1] = v.y;
            T[r][cs+i*4+2] = v.z; T[r][cs+i*4+3] = v.w;
        }
    }
    __syncthreads();
    {
        const int nr = t >> 2, ks = (t & 3) * 16;
        unsigned short hbuf[16], lbuf[16];
#pragma unroll
        for (int i = 0; i < 16; ++i) {
            float x = T[ks + i][nr];
            unsigned short hb = f2bf(x);
            hbuf[i] = hb;
            lbuf[i] = f2bf(x - bf2f(hb));
        }
        unsigned short* dh = Wt + mat*131072 + (n0+nr)*256 + k0 + ks;
        *(s16x8*)dh           = *(const s16x8*)hbuf;
        *(s16x8*)(dh+8)       = *(const s16x8*)(hbuf+8);
        *(s16x8*)(dh+65536)   = *(const s16x8*)lbuf;
        *(s16x8*)(dh+65536+8) = *(const s16x8*)(lbuf+8);
    }
}

// ---------------------------------------------------------------------------
// Kernel 2: X fp32 (8192x256) -> Xh, Xl bf16 row-major (split)
// ---------------------------------------------------------------------------
__global__ __launch_bounds__(256) void xsplit_kernel(
    const float* __restrict__ X,
    unsigned short* __restrict__ Xh, unsigned short* __restrict__ Xl)
{
    const size_t i = ((size_t)blockIdx.x * 256 + threadIdx.x) * 8;
    float4 a = *(const float4*)(X + i);
    float4 b = *(const float4*)(X + i + 4);
    const float v[8] = {a.x, a.y, a.z, a.w, b.x, b.y, b.z, b.w};
    unsigned short hb[8], lb[8];
#pragma unroll
    for (int j = 0; j < 8; ++j) {
        hb[j] = f2bf(v[j]);
        lb[j] = f2bf(v[j] - bf2f(hb[j]));
    }
    *(s16x8*)(Xh + i) = *(const s16x8*)hb;
    *(s16x8*)(Xl + i) = *(const s16x8*)lb;
}

// ---------------------------------------------------------------------------
// Kernel 3: QKV projection via MFMA, 3-term split bf16 (~fp32 accuracy).
// Swapped orientation: D[feat][node] = Wt[feat][k] * X[node][k].
// Block: 32 nodes x 256 feats, one matrix (blockIdx.y: 0=Q,1=K,2=V).
// Epilogue writes Q (scaled, split hi/lo), K bf16 node-major (B,H,N,DH),
// V bf16 transposed (B,H,DH,N).
// ---------------------------------------------------------------------------
__global__ __launch_bounds__(256) void qkv_mfma_kernel(
    const unsigned short* __restrict__ Xh, const unsigned short* __restrict__ Xl,
    const unsigned short* __restrict__ Wt,
    const float* __restrict__ bq, const float* __restrict__ bk, const float* __restrict__ bv,
    unsigned short* __restrict__ Qh, unsigned short* __restrict__ Ql,
    unsigned short* __restrict__ Kb, unsigned short* __restrict__ Vt)
{
    const int n0 = blockIdx.x * 32;
    const int mat = blockIdx.y;
    const int t = threadIdx.x, lane = t & 63, wid = t >> 6;
    const int l15 = lane & 15, hi = lane >> 4, hi4 = hi * 4;

    const unsigned short* Wh = Wt + mat * 131072;
    const unsigned short* Wl = Wh + 65536;
    const float* bias = (mat==0) ? bq : (mat==1) ? bk : bv;

    f32x4 acc[4][2];
#pragma unroll
    for (int rt = 0; rt < 4; ++rt)
#pragma unroll
        for (int c = 0; c < 2; ++c) acc[rt][c] = (f32x4){0.f,0.f,0.f,0.f};

#pragma unroll
    for (int k0 = 0; k0 < 256; k0 += 32) {
        s16x8 bhf[2], blf[2];
#pragma unroll
        for (int c = 0; c < 2; ++c) {
            const size_t off = (size_t)(n0 + c*16 + l15)*256 + k0 + hi*8;
            bhf[c] = *(const s16x8*)(Xh + off);
            blf[c] = *(const s16x8*)(Xl + off);
        }
#pragma unroll
        for (int rt = 0; rt < 4; ++rt) {
            const size_t woff = (size_t)(wid*64 + rt*16 + l15)*256 + k0 + hi*8;
            const s16x8 ah = *(const s16x8*)(Wh + woff);
            const s16x8 al = *(const s16x8*)(Wl + woff);
#pragma unroll
            for (int c = 0; c < 2; ++c) {
                acc[rt][c] = __builtin_amdgcn_mfma_f32_16x16x32_bf16(ah, bhf[c], acc[rt][c], 0,0,0);
                acc[rt][c] = __builtin_amdgcn_mfma_f32_16x16x32_bf16(al, bhf[c], acc[rt][c], 0,0,0);
                acc[rt][c] = __builtin_amdgcn_mfma_f32_16x16x32_bf16(ah, blf[c], acc[rt][c], 0,0,0);
            }
        }
    }

#pragma unroll
    for (int rt = 0; rt < 4; ++rt) {
        const int f0 = wid*64 + rt*16 + hi4;      // 4 consecutive feats (f0..f0+3)
        const int hh = f0 >> 5, d0 = f0 & 31;
        const float4 bs4 = *(const float4*)&bias[f0];
        const float bsa[4] = {bs4.x, bs4.y, bs4.z, bs4.w};
#pragma unroll
        for (int c = 0; c < 2; ++c) {
            const int g = n0 + c*16 + l15;        // global node row
            const int b = g >> 10, nn = g & (NN-1);
            if (mat == 0) {
                ushort4 qh4, ql4;
#pragma unroll
                for (int r = 0; r < 4; ++r) {
                    float q = (acc[rt][c][r] + bsa[r]) * QK_SCALE;
                    unsigned short hb = f2bf(q);
                    ((unsigned short*)&qh4)[r] = hb;
                    ((unsigned short*)&ql4)[r] = f2bf(q - bf2f(hb));
                }
                const size_t base = ((size_t)(b*NH + hh)*NN + nn)*DH + d0;
                *(ushort4*)&Qh[base] = qh4;
                *(ushort4*)&Ql[base] = ql4;
            } else if (mat == 1) {
                ushort4 kb4;
#pragma unroll
                for (int r = 0; r < 4; ++r)
                    ((unsigned short*)&kb4)[r] = f2bf(acc[rt][c][r] + bsa[r]);
                const size_t base = ((size_t)(b*NH + hh)*NN + nn)*DH + d0;
                *(ushort4*)&Kb[base] = kb4;
            } else {
#pragma unroll
                for (int r = 0; r < 4; ++r)
                    Vt[((size_t)(b*NH + hh)*DH + d0 + r)*NN + nn] =
                        f2bf(acc[rt][c][r] + bsa[r]);
            }
        }
    }
}

// ---------------------------------------------------------------------------
// Kernel 4: flash attention, ZERO LDS / ZERO barriers.
// Key-permutation sigma(kt,s) = 32(kt&1) + 8(s>>2) + 4(kt>>1) + (s&3) makes the
// QK^T output registers exactly the PV A-fragment layout (P stays in-lane).
// K/V/E fragments read straight from global (L1/L2-resident).
// Softmax reduce over {lane^16, lane^32}; defer-max (THR=8) skips O-rescale.
// b = bid&7: round-robin XCD placement pins each batch's 4MB E-slice to one L2.
// ---------------------------------------------------------------------------
__global__ __launch_bounds__(256) void attn_kernel(
    const unsigned short* __restrict__ Qh, const unsigned short* __restrict__ Ql,
    const unsigned short* __restrict__ Kb, const unsigned short* __restrict__ Vt,
    const float* __restrict__ Eg, const float* __restrict__ We,
    unsigned short* __restrict__ AOh, unsigned short* __restrict__ AOl)
{
    const int bid = blockIdx.x;
    const int b = bid & 7, h = (bid >> 3) & 7, qt = bid >> 6;
    const int q0 = qt * 64;
    const int t = threadIdx.x, lane = t & 63, wid = t >> 6;
    const int l15 = lane & 15, hi = lane >> 4, hi4 = hi * 4;

    const float we_h = We[h];
    const size_t kvbase = (size_t)(b*NH + h) * NN * DH;   // same offset for Kb/Qh/Vt
    const int qrow = q0 + wid*16 + l15;
    const s16x8 qh_f = *(const s16x8*)(Qh + kvbase + (size_t)qrow*DH + hi*8);
    const s16x8 ql_f = *(const s16x8*)(Ql + kvbase + (size_t)qrow*DH + hi*8);
    const float* Ep = Eg + ((size_t)b << 20) + ((size_t)qrow << 10);
    const int rbase = 8*(l15 >> 2) + (l15 & 3);           // sigma row part for A-frag

    float m_run = -3.0e38f, l_run = 0.f;
    f32x4 O0 = (f32x4){0.f,0.f,0.f,0.f}, O1 = (f32x4){0.f,0.f,0.f,0.f};

    for (int mt = 0; mt < 16; ++mt) {
        const int m0 = mt * 64;
        float s[16];
#pragma unroll
        for (int kt = 0; kt < 4; ++kt) {
            const int koff = 32*(kt & 1) + 4*(kt >> 1);
            const s16x8 kfr = *(const s16x8*)(Kb + kvbase + (size_t)(m0 + koff + rbase)*DH + hi*8);
            f32x4 sc = (f32x4){0.f,0.f,0.f,0.f};
            sc = __builtin_amdgcn_mfma_f32_16x16x32_bf16(kfr, ql_f, sc, 0,0,0);
            sc = __builtin_amdgcn_mfma_f32_16x16x32_bf16(kfr, qh_f, sc, 0,0,0);
            const float4 e4 = *(const float4*)(Ep + m0 + koff + 8*hi);
            s[kt*4+0] = fmaf(e4.x, we_h, sc[0]);
            s[kt*4+1] = fmaf(e4.y, we_h, sc[1]);
            s[kt*4+2] = fmaf(e4.z, we_h, sc[2]);
            s[kt*4+3] = fmaf(e4.w, we_h, sc[3]);
        }

        // online softmax (lane's q-row = l15; keys split across hi groups)
        float tm = s[0];
#pragma unroll
        for (int i = 1; i < 16; ++i) tm = fmaxf(tm, s[i]);
        tm = fmaxf(tm, __shfl_xor(tm, 16));
        tm = fmaxf(tm, __shfl_xor(tm, 32));
        if (!__all(tm <= m_run + 8.0f)) {      // defer-max: skip rescale if growth small
            const float mn = fmaxf(m_run, tm);
            const float alpha = __expf(m_run - mn);
            m_run = mn;
            l_run *= alpha;
            const float a0 = __shfl(alpha, hi4+0);
            const float a1 = __shfl(alpha, hi4+1);
            const float a2 = __shfl(alpha, hi4+2);
            const float a3 = __shfl(alpha, hi4+3);
            O0[0]*=a0; O0[1]*=a1; O0[2]*=a2; O0[3]*=a3;
            O1[0]*=a0; O1[1]*=a1; O1[2]*=a2; O1[3]*=a3;
        }
        float ps = 0.f;
#pragma unroll
        for (int i = 0; i < 16; ++i) { s[i] = __expf(s[i] - m_run); ps += s[i]; }
        ps += __shfl_xor(ps, 16);
        ps += __shfl_xor(ps, 32);
        l_run += ps;

        // pack P (in-lane, thanks to sigma): pfr_c = [s[4c..4c+3], s[4c+8..4c+11]]
        union { s16x8 v; unsigned int u[4]; } pf0, pf1;
        pf0.u[0] = packbf(s[0],  s[1]);   pf0.u[1] = packbf(s[2],  s[3]);
        pf0.u[2] = packbf(s[8],  s[9]);   pf0.u[3] = packbf(s[10], s[11]);
        pf1.u[0] = packbf(s[4],  s[5]);   pf1.u[1] = packbf(s[6],  s[7]);
        pf1.u[2] = packbf(s[12], s[13]);  pf1.u[3] = packbf(s[14], s[15]);

        // PV: O[q][d] += P[q][key] * Vt[d][key]
        {
            const s16x8 v00 = *(const s16x8*)(Vt + kvbase + (size_t)l15*NN      + m0      + hi*8);
            const s16x8 v01 = *(const s16x8*)(Vt + kvbase + (size_t)(16+l15)*NN + m0      + hi*8);
            O0 = __builtin_amdgcn_mfma_f32_16x16x32_bf16(pf0.v, v00, O0, 0,0,0);
            O1 = __builtin_amdgcn_mfma_f32_16x16x32_bf16(pf0.v, v01, O1, 0,0,0);
            const s16x8 v10 = *(const s16x8*)(Vt + kvbase + (size_t)l15*NN      + m0 + 32 + hi*8);
            const s16x8 v11 = *(const s16x8*)(Vt + kvbase + (size_t)(16+l15)*NN + m0 + 32 + hi*8);
            O0 = __builtin_amdgcn_mfma_f32_16x16x32_bf16(pf1.v, v10, O0, 0,0,0);
            O1 = __builtin_amdgcn_mfma_f32_16x16x32_bf16(pf1.v, v11, O1, 0,0,0);
        }
    }

    // epilogue: normalize, split hi/lo, write AO (B,N,H*DH) node-major bf16
    float linv[4];
#pragma unroll
    for (int r = 0; r < 4; ++r) linv[r] = 1.0f / __shfl(l_run, hi4 + r);
#pragma unroll
    for (int r = 0; r < 4; ++r) {
        const size_t node = (size_t)b*NN + q0 + wid*16 + hi4 + r;
        {
            const float o = O0[r] * linv[r];
            const unsigned short hb = f2bf(o);
            const size_t idx = node*DOUT + h*DH + l15;
            AOh[idx] = hb; AOl[idx] = f2bf(o - bf2f(hb));
        }
        {
            const float o = O1[r] * linv[r];
            const unsigned short hb = f2bf(o);
            const size_t idx = node*DOUT + h*DH + 16 + l15;
            AOh[idx] = hb; AOl[idx] = f2bf(o - bf2f(hb));
        }
    }
}

// ---------------------------------------------------------------------------
// Kernel 5: out projection via MFMA (3-term split) + bias + residual -> d_out
// Block: 32 nodes x 128 feats (blockIdx.y = feat half) for occupancy.
// ---------------------------------------------------------------------------
__global__ __launch_bounds__(256) void oproj_kernel(
    const unsigned short* __restrict__ AOh, const unsigned short* __restrict__ AOl,
    const unsigned short* __restrict__ Wt,
    const float* __restrict__ bo, const float* __restrict__ X0,
    float* __restrict__ out)
{
    const int n0 = blockIdx.x * 32;
    const int fh = blockIdx.y;
    const int t = threadIdx.x, lane = t & 63, wid = t >> 6;
    const int l15 = lane & 15, hi = lane >> 4, hi4 = hi * 4;

    const unsigned short* Wh = Wt + 3 * 131072;
    const unsigned short* Wl = Wh + 65536;

    f32x4 acc[2][2];
#pragma unroll
    for (int rt = 0; rt < 2; ++rt)
#pragma unroll
        for (int c = 0; c < 2; ++c) acc[rt][c] = (f32x4){0.f,0.f,0.f,0.f};

#pragma unroll
    for (int k0 = 0; k0 < 256; k0 += 32) {
        s16x8 bhf[2], blf[2];
#pragma unroll
        for (int c = 0; c < 2; ++c) {
            const size_t off = (size_t)(n0 + c*16 + l15)*256 + k0 + hi*8;
            bhf[c] = *(const s16x8*)(AOh + off);
            blf[c] = *(const s16x8*)(AOl + off);
        }
#pragma unroll
        for (int rt = 0; rt < 2; ++rt) {
            const size_t woff = (size_t)(fh*128 + wid*32 + rt*16 + l15)*256 + k0 + hi*8;
            const s16x8 ah = *(const s16x8*)(Wh + woff);
            const s16x8 al = *(const s16x8*)(Wl + woff);
#pragma unroll
            for (int c = 0; c < 2; ++c) {
                acc[rt][c] = __builtin_amdgcn_mfma_f32_16x16x32_bf16(ah, bhf[c], acc[rt][c], 0,0,0);
                acc[rt][c] = __builtin_amdgcn_mfma_f32_16x16x32_bf16(al, bhf[c], acc[rt][c], 0,0,0);
                acc[rt][c] = __builtin_amdgcn_mfma_f32_16x16x32_bf16(ah, blf[c], acc[rt][c], 0,0,0);
            }
        }
    }

#pragma unroll
    for (int rt = 0; rt < 2; ++rt) {
        const int f0 = fh*128 + wid*32 + rt*16 + hi4;
        const float4 bs4 = *(const float4*)&bo[f0];
#pragma unroll
        for (int c = 0; c < 2; ++c) {
            const size_t g = n0 + c*16 + l15;
            const float4 r4 = *(const float4*)&X0[g*256 + f0];
            float4 o;
            o.x = acc[rt][c][0] + bs4.x + r4.x;
            o.y = acc[rt][c][1] + bs4.y + r4.y;
            o.z = acc[rt][c][2] + bs4.z + r4.z;
            o.w = acc[rt][c][3] + bs4.w + r4.w;
            *(float4*)&out[g*256 + f0] = o;
        }
    }
}

// ---------------------------------------------------------------------------
// Kernel 6: in-place LayerNorm, 4 rows per block (1 wave per row)
// ---------------------------------------------------------------------------
__global__ __launch_bounds__(256) void ln_kernel(
    float* __restrict__ X, const float* __restrict__ g, const float* __restrict__ bta)
{
    const int row = blockIdx.x * 4 + (threadIdx.x >> 6);
    const int l = threadIdx.x & 63;
    float4 v = *(const float4*)&X[(size_t)row*DOUT + l*4];

    float s = v.x + v.y + v.z + v.w;
#pragma unroll
    for (int m = 1; m < 64; m <<= 1) s += __shfl_xor(s, m);
    float mu = s * (1.0f / 256.0f);

    float dx = v.x - mu, dy = v.y - mu, dz = v.z - mu, dw = v.w - mu;
    float ss = dx*dx + dy*dy + dz*dz + dw*dw;
#pragma unroll
    for (int m = 1; m < 64; m <<= 1) ss += __shfl_xor(ss, m);
    float r = rsqrtf(ss * (1.0f / 256.0f) + LN_EPS);

    float4 g4 = *(const float4*)&g[l*4];
    float4 b4 = *(const float4*)&bta[l*4];
    float4 o;
    o.x = dx * r * g4.x + b4.x;
    o.y = dy * r * g4.y + b4.y;
    o.z = dz * r * g4.z + b4.z;
    o.w = dw * r * g4.w + b4.w;
    *(float4*)&X[(size_t)row*DOUT + l*4] = o;
}

// ---------------------------------------------------------------------------
extern "C" void kernel_launch(void* const* d_in, const int* in_sizes, int n_in,
                              void* d_out, int out_size, void* d_ws, size_t ws_size,
                              hipStream_t stream) {
    const float* X    = (const float*)d_in[0];
    const float* E    = (const float*)d_in[1];
    const float* Wq   = (const float*)d_in[2];
    const float* bq   = (const float*)d_in[3];
    const float* Wk   = (const float*)d_in[4];
    const float* bk   = (const float*)d_in[5];
    const float* Wv   = (const float*)d_in[6];
    const float* bv   = (const float*)d_in[7];
    const float* We   = (const float*)d_in[8];
    // d_in[9] = be: constant over softmax axis -> cancels exactly; dropped
    const float* Wo   = (const float*)d_in[10];
    const float* bo   = (const float*)d_in[11];
    const float* gam  = (const float*)d_in[12];
    const float* bet  = (const float*)d_in[13];
    float* out = (float*)d_out;

    // workspace (shorts), ~25 MB total:
    // [Xh | AOh][Xl | AOl][Qh][Ql][Kb][Vt][Wt: 4 x (hi 64K + lo 64K)]
    const size_t TENS = (size_t)NB * NN * DOUT;   // 2,097,152
    unsigned short* SH = (unsigned short*)d_ws;
    unsigned short* Xh = SH;                 // aliased as AOh after qkv done
    unsigned short* Xl = SH + TENS;          // aliased as AOl
    unsigned short* Qh = SH + 2*TENS;
    unsigned short* Ql = SH + 3*TENS;
    unsigned short* Kb = SH + 4*TENS;
    unsigned short* Vt = SH + 5*TENS;
    unsigned short* Wt = SH + 6*TENS;        // 524,288 shorts

    wsplit_kernel<<<dim3(4,4,4), 256, 0, stream>>>(Wq, Wk, Wv, Wo, Wt);
    xsplit_kernel<<<1024, 256, 0, stream>>>(X, Xh, Xl);
    qkv_mfma_kernel<<<dim3(256,3), 256, 0, stream>>>(Xh, Xl, Wt, bq, bk, bv, Qh, Ql, Kb, Vt);
    attn_kernel<<<NB*NH*(NN/64), 256, 0, stream>>>(Qh, Ql, Kb, Vt, E, We, Xh, Xl);
    oproj_kernel<<<dim3(256,2), 256, 0, stream>>>(Xh, Xl, Wt, bo, X, out);
    ln_kernel<<<NB*NN/4, 256, 0, stream>>>(out, gam, bet);
}